// Round 1
// baseline (296.191 us; speedup 1.0000x reference)
//
#include <hip/hip_runtime.h>

// Problem constants (fixed by setup_inputs)
#define CLIP 4096
#define H1   2048
#define H2   1024
#define RN   4096
#define H_STEP 2.44140625f   // r_i = H_STEP*(i+1), exact (linspace step == R_MAX/rn)
#define X1   32768           // stage-1 grid points per l
#define P2   16              // stage-2 multisection points per eigenvalue

// ---------------- Sturm count: #eigenvalues < x of tridiag(d, -0.5) ----------
__device__ __forceinline__ int sturm_count(const float* __restrict__ d, float x) {
    float q = __builtin_inff();   // rcp(inf)=0 -> first pivot = d[0]-x
    int cnt = 0;
#pragma unroll 8
    for (int i = 0; i < RN; ++i) {
        float t = d[i] - x;                       // d[i] uniform -> s_load
        q = t - 0.25f * __builtin_amdgcn_rcpf(q); // e^2 = 0.25
        cnt += (int)(__float_as_uint(q) >> 31);   // count negative pivots
    }
    return cnt;
}

// ---------------- GEMV: y[j] = sum_i x[i]*W[i,j]  (split-K partials) ---------
__global__ void gemv_part(const float* __restrict__ W, const float* __restrict__ x,
                          float* __restrict__ part, int N, int chunk) {
    int j = (blockIdx.x * blockDim.x + threadIdx.x) << 2;
    int i0 = blockIdx.y * chunk, i1 = i0 + chunk;
    float4 acc = make_float4(0.f, 0.f, 0.f, 0.f);
    const float* Wp = W + (size_t)i0 * N + j;
    for (int i = i0; i < i1; ++i) {
        float xi = x[i];                                   // uniform -> s_load
        float4 w = *reinterpret_cast<const float4*>(Wp);
        acc.x = fmaf(xi, w.x, acc.x);
        acc.y = fmaf(xi, w.y, acc.y);
        acc.z = fmaf(xi, w.z, acc.z);
        acc.w = fmaf(xi, w.w, acc.w);
        Wp += N;
    }
    *reinterpret_cast<float4*>(part + (size_t)blockIdx.y * N + j) = acc;
}

__global__ void gemv_fin(const float* __restrict__ part, const float* __restrict__ b,
                         float* __restrict__ y, int N, int nch, int relu) {
    int j = blockIdx.x * 256 + threadIdx.x;
    float s = b[j];
    for (int c = 0; c < nch; ++c) s += part[(size_t)c * N + j];
    if (relu) s = fmaxf(s, 0.f);
    y[j] = s;
}

// ---------------- diag arrays for l=0,1 --------------------------------------
__global__ void prep_d(const float* __restrict__ ptl, float* __restrict__ d0,
                       float* __restrict__ d1) {
    int i = blockIdx.x * 256 + threadIdx.x;
    float p = ptl[i];
    float r = H_STEP * (float)(i + 1);
    d0[i] = 1.0f + p;
    d1[i] = 1.0f + p + 2.0f / (r * r);
}

// ---------------- Gershgorin bounds (single block) ---------------------------
__global__ void bounds_kernel(const float* __restrict__ ptl, float* __restrict__ bounds) {
    __shared__ float smin[16], smax[16];
    int tid = threadIdx.x;
    float mn = 1e30f, mx = -1e30f;
    for (int i = tid; i < RN; i += 1024) {
        float v = ptl[i];
        mn = fminf(mn, v); mx = fmaxf(mx, v);
    }
    for (int off = 32; off; off >>= 1) {
        mn = fminf(mn, __shfl_down(mn, off));
        mx = fmaxf(mx, __shfl_down(mx, off));
    }
    if ((tid & 63) == 0) { smin[tid >> 6] = mn; smax[tid >> 6] = mx; }
    __syncthreads();
    if (tid == 0) {
        float lo = 1e30f, hi = -1e30f;
        for (int w = 0; w < 16; ++w) { lo = fminf(lo, smin[w]); hi = fmaxf(hi, smax[w]); }
        // lo: min(1+ptl) - 1 ;  hi: 1 + max ptl + 2/r_0^2 + 1
        lo = lo - 1e-3f;
        hi = hi + 2.0f + 0.33554432f + 1e-3f;
        bounds[0] = lo;
        bounds[1] = (hi - lo) / (float)X1;   // cell width
    }
}

// ---------------- Stage 1: counts on uniform grid ----------------------------
__global__ void stage1(const float* __restrict__ d0, const float* __restrict__ d1,
                       const float* __restrict__ bounds, int* __restrict__ counts) {
    int t = blockIdx.x * 256 + threadIdx.x;       // 2*X1 threads
    int l = t >> 15, j = t & (X1 - 1);
    const float* d = l ? d1 : d0;
    float x = bounds[0] + bounds[1] * (float)j;
    counts[t] = sturm_count(d, x);
}

// ---------------- Brackets: last grid point with count <= k ------------------
__global__ void brackets_kernel(const int* __restrict__ counts, const float* __restrict__ bounds,
                                float* __restrict__ brk) {
    int e = blockIdx.x * 256 + threadIdx.x;       // 8192 eigenvalues (l,k)
    int l = e >> 12, k = e & (RN - 1);
    const int* c = counts + (l << 15);
    int loi = 0, hii = X1 - 1;
    while (loi < hii) {
        int mid = (loi + hii + 1) >> 1;
        if (c[mid] <= k) loi = mid; else hii = mid - 1;
    }
    while (loi > 0 && c[loi] > k) --loi;               // robustness vs tiny
    while (loi < X1 - 1 && c[loi + 1] <= k) ++loi;     // non-monotonicity
    brk[e] = bounds[0] + bounds[1] * (float)loi;
}

// ---------------- Stage 2: multisection inside each bracket ------------------
__global__ void stage2(const float* __restrict__ d0, const float* __restrict__ d1,
                       const float* __restrict__ bounds, const float* __restrict__ brk,
                       int* __restrict__ c2) {
    int t = blockIdx.x * 256 + threadIdx.x;       // 8192*P2 threads
    int e = t >> 4, p = t & (P2 - 1);
    int l = e >> 12;
    const float* d = l ? d1 : d0;
    float x = brk[e] + bounds[1] * ((float)(p + 1) * (1.0f / 17.0f));
    c2[t] = sturm_count(d, x);
}

// ---------------- Finalize: midpoint of crossing sub-interval ----------------
__global__ void finalize(const int* __restrict__ c2, const float* __restrict__ bounds,
                         const float* __restrict__ brk, float* __restrict__ out) {
    int e = blockIdx.x * 256 + threadIdx.x;       // 8192
    int k = e & (RN - 1);
    float a = brk[e], cell = bounds[1];
    const int* c = c2 + (e << 4);
    int p = P2;
    for (int i = 0; i < P2; ++i) {
        if (c[i] > k) { p = i; break; }
    }
    float x0 = a + cell * ((float)p * (1.0f / 17.0f));        // left  = x_{p-1} (or a)
    float x1 = a + cell * ((float)(p + 1) * (1.0f / 17.0f));  // right = x_p (or a+cell)
    out[e] = 0.5f * (x0 + x1);
}

extern "C" void kernel_launch(void* const* d_in, const int* in_sizes, int n_in,
                              void* d_out, int out_size, void* d_ws, size_t ws_size,
                              hipStream_t stream) {
    const float* energy = (const float*)d_in[0];
    const float* W1 = (const float*)d_in[1];
    const float* b1 = (const float*)d_in[2];
    const float* W2 = (const float*)d_in[3];
    const float* b2 = (const float*)d_in[4];
    const float* W3 = (const float*)d_in[5];
    const float* b3 = (const float*)d_in[6];
    float* out = (float*)d_out;                 // [RN] ptl, then [2*RN] eigenvalues

    float* ws = (float*)d_ws;
    float* part   = ws;                         // 131072 f32 (max split-K partials)
    float* h1     = ws + 131072;                // 2048
    float* h2     = h1 + H1;                    // 1024
    float* d0     = h2 + H2;                    // 4096
    float* d1     = d0 + RN;                    // 4096
    float* bounds = d1 + RN;                    // 2 (+pad)
    int*   counts = (int*)(bounds + 8);         // 65536 i32
    float* brk    = (float*)(counts + 2 * X1);  // 8192 f32
    int*   c2     = (int*)(brk + 2 * RN);       // 131072 i32

    // ---- MLP: 3 GEMVs with split-K ----
    gemv_part<<<dim3(H1 / 1024, 64), 256, 0, stream>>>(W1, energy, part, H1, CLIP / 64);
    gemv_fin<<<H1 / 256, 256, 0, stream>>>(part, b1, h1, H1, 64, 1);

    gemv_part<<<dim3(H2 / 1024, 64), 256, 0, stream>>>(W2, h1, part, H2, H1 / 64);
    gemv_fin<<<H2 / 256, 256, 0, stream>>>(part, b2, h2, H2, 64, 1);

    gemv_part<<<dim3(RN / 1024, 32), 256, 0, stream>>>(W3, h2, part, RN, H2 / 32);
    gemv_fin<<<RN / 256, 256, 0, stream>>>(part, b3, out, RN, 32, 0);  // ptl -> d_out[0:RN]

    // ---- Eigenvalues via Sturm bisection/multisection ----
    prep_d<<<RN / 256, 256, 0, stream>>>(out, d0, d1);
    bounds_kernel<<<1, 1024, 0, stream>>>(out, bounds);
    stage1<<<2 * X1 / 256, 256, 0, stream>>>(d0, d1, bounds, counts);
    brackets_kernel<<<2 * RN / 256, 256, 0, stream>>>(counts, bounds, brk);
    stage2<<<2 * RN * P2 / 256, 256, 0, stream>>>(d0, d1, bounds, brk, c2);
    finalize<<<2 * RN / 256, 256, 0, stream>>>(c2, bounds, brk, out + RN);
}

// Round 2
// 146.531 us; speedup vs baseline: 2.0214x; 2.0214x over previous
//
#include <hip/hip_runtime.h>

// Problem constants (fixed by setup_inputs)
#define CLIP 4096
#define H1   2048
#define H2   1024
#define RN   4096
#define H_STEP 2.44140625f   // r_i = H_STEP*(i+1), exact (linspace step == R_MAX/rn)
#define G1   32768           // grid points per l (single-stage multisection)

// ---------------- GEMV: y[j] = sum_i x[i]*W[i,j]  (split-K partials) ---------
__global__ void gemv_part(const float* __restrict__ W, const float* __restrict__ x,
                          float* __restrict__ part, int N, int chunk) {
    int j = (blockIdx.x * blockDim.x + threadIdx.x) << 2;
    int i0 = blockIdx.y * chunk, i1 = i0 + chunk;
    float4 acc = make_float4(0.f, 0.f, 0.f, 0.f);
    const float* Wp = W + (size_t)i0 * N + j;
    for (int i = i0; i < i1; ++i) {
        float xi = x[i];                                   // uniform -> s_load
        float4 w = *reinterpret_cast<const float4*>(Wp);
        acc.x = fmaf(xi, w.x, acc.x);
        acc.y = fmaf(xi, w.y, acc.y);
        acc.z = fmaf(xi, w.z, acc.z);
        acc.w = fmaf(xi, w.w, acc.w);
        Wp += N;
    }
    *reinterpret_cast<float4*>(part + (size_t)blockIdx.y * N + j) = acc;
}

__global__ void gemv_fin(const float* __restrict__ part, const float* __restrict__ b,
                         float* __restrict__ y, int N, int nch, int relu) {
    int j = blockIdx.x * 256 + threadIdx.x;
    float s = b[j];
    for (int c = 0; c < nch; ++c) s += part[(size_t)c * N + j];
    if (relu) s = fmaxf(s, 0.f);
    y[j] = s;
}

// ------------- prep: d0/d1 arrays + Gershgorin bounds (one block) ------------
__global__ void prep(const float* __restrict__ ptl, float* __restrict__ d0,
                     float* __restrict__ d1, float* __restrict__ bounds) {
    __shared__ float smn[16], smx[16];
    int tid = threadIdx.x;
    float mn = 1e30f, mx = -1e30f;
    for (int i = tid; i < RN; i += 1024) {
        float p = ptl[i];
        float r = H_STEP * (float)(i + 1);
        d0[i] = 1.0f + p;
        d1[i] = 1.0f + p + 2.0f / (r * r);
        mn = fminf(mn, p); mx = fmaxf(mx, p);
    }
    for (int off = 32; off; off >>= 1) {
        mn = fminf(mn, __shfl_down(mn, off));
        mx = fmaxf(mx, __shfl_down(mx, off));
    }
    if ((tid & 63) == 0) { smn[tid >> 6] = mn; smx[tid >> 6] = mx; }
    __syncthreads();
    if (tid == 0) {
        float lo = 1e30f, hi = -1e30f;
        for (int w = 0; w < 16; ++w) { lo = fminf(lo, smn[w]); hi = fmaxf(hi, smx[w]); }
        lo = lo - 1e-3f;                         // < lambda_min (Gershgorin)
        hi = hi + 2.0f + 0.33554432f + 1e-3f;    // > lambda_max (2/r0^2 = 0.3355)
        bounds[0] = lo;
        bounds[1] = (hi - lo) / (float)G1;       // cell width
    }
}

// ---------------- Sturm via characteristic-polynomial recurrence -------------
// p_i = (d_i - x) p_{i-1} - 0.25 p_{i-2};  #eigs < x = sign changes in {p_i}.
// No division: critical path is one FMA per step. Rescale every 16 steps.
#define STEP(dv)                                                            \
    {                                                                       \
        float t = (dv) - x;                                                 \
        float p = fmaf(t, pm1, -0.25f * pm2);                               \
        cnt += (__float_as_uint(p) ^ __float_as_uint(pm1)) >> 31;           \
        pm2 = pm1; pm1 = p;                                                 \
    }

__global__ __launch_bounds__(256) void stage1(const float* __restrict__ d0,
                                              const float* __restrict__ d1,
                                              const float* __restrict__ bounds,
                                              int* __restrict__ counts) {
    __shared__ alignas(16) float ds[RN];
    const float* dsrc = blockIdx.y ? d1 : d0;
    for (int i = threadIdx.x; i < RN / 4; i += 256)
        reinterpret_cast<float4*>(ds)[i] = reinterpret_cast<const float4*>(dsrc)[i];
    __syncthreads();

    int j = blockIdx.x * 256 + threadIdx.x;          // grid index within l
    float x = bounds[0] + bounds[1] * (float)j;

    float pm1 = 1.0f, pm2 = 0.0f;
    unsigned cnt = 0;
    const float4* ds4 = reinterpret_cast<const float4*>(ds);
#pragma unroll 4
    for (int ii = 0; ii < RN / 16; ++ii) {
        float4 a = ds4[ii * 4 + 0];
        float4 b = ds4[ii * 4 + 1];
        float4 c = ds4[ii * 4 + 2];
        float4 e = ds4[ii * 4 + 3];
        STEP(a.x) STEP(a.y) STEP(a.z) STEP(a.w)
        STEP(b.x) STEP(b.y) STEP(b.z) STEP(b.w)
        STEP(c.x) STEP(c.y) STEP(c.z) STEP(c.w)
        STEP(e.x) STEP(e.y) STEP(e.z) STEP(e.w)
        // branchless renormalize: scale both by 2^-e(max|pm1|,|pm2|)
        unsigned a1 = __float_as_uint(pm1) & 0x7fffffffu;
        unsigned a2 = __float_as_uint(pm2) & 0x7fffffffu;
        int ee = (int)((a1 > a2 ? a1 : a2) >> 23);
        int es = 254 - ee;
        es = es < 67 ? 67 : (es > 187 ? 187 : es);   // clamp scale to 2^±60
        float s = __uint_as_float((unsigned)es << 23);
        pm1 *= s; pm2 *= s;
    }
    counts[blockIdx.y * G1 + j] = (int)cnt;
}

// ------------- final: bracket search + midpoint -> eigenvalues ---------------
__global__ void final_eig(const int* __restrict__ counts, const float* __restrict__ bounds,
                          float* __restrict__ out) {
    int e = blockIdx.x * 256 + threadIdx.x;          // 8192 eigenvalues (l,k)
    int l = e >> 12, k = e & (RN - 1);
    const int* c = counts + l * G1;
    int lo = 0, hi = G1 - 1;                         // last j with c[j] <= k
    while (lo < hi) {
        int mid = (lo + hi + 1) >> 1;
        if (c[mid] <= k) lo = mid; else hi = mid - 1;
    }
    out[e] = bounds[0] + bounds[1] * ((float)lo + 0.5f);
}

extern "C" void kernel_launch(void* const* d_in, const int* in_sizes, int n_in,
                              void* d_out, int out_size, void* d_ws, size_t ws_size,
                              hipStream_t stream) {
    const float* energy = (const float*)d_in[0];
    const float* W1 = (const float*)d_in[1];
    const float* b1 = (const float*)d_in[2];
    const float* W2 = (const float*)d_in[3];
    const float* b2 = (const float*)d_in[4];
    const float* W3 = (const float*)d_in[5];
    const float* b3 = (const float*)d_in[6];
    float* out = (float*)d_out;                 // [RN] ptl, then [2*RN] eigenvalues

    float* ws = (float*)d_ws;
    float* part   = ws;                         // 131072 f32 (split-K partials)
    float* h1     = ws + 131072;                // 2048
    float* h2     = h1 + H1;                    // 1024
    float* d0     = h2 + H2;                    // 4096
    float* d1     = d0 + RN;                    // 4096
    float* bounds = d1 + RN;                    // 2 (+pad)
    int*   counts = (int*)(bounds + 8);         // 2*G1 i32

    // ---- MLP: 3 GEMVs with split-K ----
    gemv_part<<<dim3(H1 / 1024, 64), 256, 0, stream>>>(W1, energy, part, H1, CLIP / 64);
    gemv_fin<<<H1 / 256, 256, 0, stream>>>(part, b1, h1, H1, 64, 1);

    gemv_part<<<dim3(H2 / 1024, 64), 256, 0, stream>>>(W2, h1, part, H2, H1 / 64);
    gemv_fin<<<H2 / 256, 256, 0, stream>>>(part, b2, h2, H2, 64, 1);

    gemv_part<<<dim3(RN / 1024, 32), 256, 0, stream>>>(W3, h2, part, RN, H2 / 32);
    gemv_fin<<<RN / 256, 256, 0, stream>>>(part, b3, out, RN, 32, 0);  // ptl -> d_out[0:RN]

    // ---- Eigenvalues: single-stage Sturm multisection (poly recurrence) ----
    prep<<<1, 1024, 0, stream>>>(out, d0, d1, bounds);
    stage1<<<dim3(G1 / 256, 2), 256, 0, stream>>>(d0, d1, bounds, counts);
    final_eig<<<2 * RN / 256, 256, 0, stream>>>(counts, bounds, out + RN);
}